// Round 1
// baseline (141.415 us; speedup 1.0000x reference)
//
#include <hip/hip_runtime.h>

// TINShift: out[n,t,c,hw] = x[n, t + shift[n, c/gc], c, hw] if in-range else 0.
// N=8, T=16, C=256, HW=3136, G=8, gc=32.  Pure memory-bound gather.
//
// Layout: HW=3136 floats = 784 float4 per (n,t,c) row, contiguous -> perfectly
// coalesced 16B/lane loads & stores. One block per (n,t,c) row makes the shift
// lookup and the valid/invalid branch wave-uniform (zero divergence).

#define TIN_N  8
#define TIN_T  16
#define TIN_C  256
#define TIN_HW 3136
#define TIN_G  8
#define TIN_GC (TIN_C / TIN_G)       // 32 channels per shift group
#define TIN_HW4 (TIN_HW / 4)         // 784 float4 per row

__global__ __launch_bounds__(256) void tin_shift_kernel(
    const float* __restrict__ x,
    const int*   __restrict__ shift,
    float*       __restrict__ out)
{
    // One block per (n, t, c) row.
    const int row = blockIdx.x;                 // 0 .. N*T*C-1 (32768)
    const int c   = row & (TIN_C - 1);          // C = 256 (pow2)
    const int t   = (row >> 8) & (TIN_T - 1);   // T = 16  (pow2)
    const int n   = row >> 12;                  // N*T*C/(T*C) ; T*C = 4096

    const int g  = c >> 5;                      // c / gc, gc=32
    const int s  = shift[n * TIN_G + g];        // wave-uniform scalar load
    const int ts = t + s;

    float4*       dst = reinterpret_cast<float4*>(out) + (size_t)row * TIN_HW4;
    const int tid = threadIdx.x;

    if (ts >= 0 && ts < TIN_T) {
        const size_t src_row = ((size_t)n * TIN_T + ts) * TIN_C + c;
        const float4* src = reinterpret_cast<const float4*>(x) + src_row * TIN_HW4;
        #pragma unroll
        for (int i = tid; i < TIN_HW4; i += 256) {
            dst[i] = src[i];
        }
    } else {
        const float4 z = make_float4(0.f, 0.f, 0.f, 0.f);
        #pragma unroll
        for (int i = tid; i < TIN_HW4; i += 256) {
            dst[i] = z;
        }
    }
}

extern "C" void kernel_launch(void* const* d_in, const int* in_sizes, int n_in,
                              void* d_out, int out_size, void* d_ws, size_t ws_size,
                              hipStream_t stream)
{
    const float* x     = (const float*)d_in[0];
    const int*   shift = (const int*)d_in[1];
    float*       out   = (float*)d_out;

    const int rows = TIN_N * TIN_T * TIN_C;     // 32768 blocks
    tin_shift_kernel<<<rows, 256, 0, stream>>>(x, shift, out);
}